// Round 2
// baseline (179.239 us; speedup 1.0000x reference)
//
#include <hip/hip_runtime.h>
#include <hip/hip_bf16.h>

typedef __bf16 bf16_t;
typedef __bf16 bf16x8 __attribute__((ext_vector_type(8)));
typedef float f32x4 __attribute__((ext_vector_type(4)));

#define ALPHA 8.3f
// img: [4][64][256][256] f32, depth: [4][1][256][256] f32,
// weight: [64][64][3][3] f32, bias: [1][64] f32
// out: [4][64][254][254] f32

// Repack weight [oc][c][3][3] (f32) -> bf16 A-fragment order
// [tap(9)][chunk(2)][mblock(4)][lane(64)][j(8)]
//   oc = mblock*16 + (lane&15), c = chunk*32 + (lane>>4)*8 + j
__global__ void repack_w(const float* __restrict__ w, bf16_t* __restrict__ w2) {
    int idx = blockIdx.x * 256 + threadIdx.x;  // 0..36863
    if (idx >= 9 * 2 * 4 * 64 * 8) return;
    int j     = idx & 7;
    int lane  = (idx >> 3) & 63;
    int m     = (idx >> 9) & 3;
    int chunk = (idx >> 11) & 1;
    int tap   = idx >> 12;
    int oc = m * 16 + (lane & 15);
    int c  = chunk * 32 + (lane >> 4) * 8 + j;
    int kt = tap / 3, lt = tap % 3;
    w2[idx] = (bf16_t)w[((oc * 64 + c) * 3 + kt) * 3 + lt];
}

// One wave computes a 64(oc) x 64(q) output tile for a fixed (b, p) row.
// GEMM: M=64 (oc), N=64 (pixels), K=576 (= 9 taps x 64 ch), B' = img * dw.
__global__ __launch_bounds__(256) void depthconv_mfma(
    const float* __restrict__ img, const float* __restrict__ depth,
    const bf16_t* __restrict__ w2, const float* __restrict__ bias,
    float* __restrict__ out)
{
    const int wv   = threadIdx.x >> 6;
    const int lane = threadIdx.x & 63;
    const int n    = lane & 15;
    const int quad = lane >> 4;

    int t   = blockIdx.x * 4 + wv;      // wave-tile id, 0..4063
    int tq  = t & 3;
    int p   = (t >> 2) % 254;
    int b   = (t >> 2) / 254;
    int q0  = (tq == 3) ? 190 : tq * 64;   // last tile overlaps: benign dup writes

    const float* dep  = depth + (size_t)b * 65536;
    const float* imgb = img + (size_t)b * 64 * 65536;

    // center depth per n-block (c0 = 1)
    float dc[4];
#pragma unroll
    for (int i = 0; i < 4; ++i)
        dc[i] = dep[(p + 1) * 256 + (q0 + i * 16 + n + 1)];

    f32x4 acc[4][4];
#pragma unroll
    for (int m = 0; m < 4; ++m)
#pragma unroll
        for (int i = 0; i < 4; ++i)
            acc[m][i] = (f32x4){0.f, 0.f, 0.f, 0.f};

    for (int kt = 0; kt < 3; ++kt) {
        for (int lt = 0; lt < 3; ++lt) {
            const int tap = kt * 3 + lt;
            // dw per n-block: depends on output pixel (q0+i*16+n), not channel
            float dwv[4];
#pragma unroll
            for (int i = 0; i < 4; ++i) {
                float d = dep[(p + kt) * 256 + (q0 + i * 16 + n + lt)];
                dwv[i] = __expf(-ALPHA * fabsf(d - dc[i]));
            }
#pragma unroll
            for (int chunk = 0; chunk < 2; ++chunk) {
                // A fragments: 4 m-blocks, 16B contiguous per lane
                bf16x8 a[4];
                const bf16x8* w2p =
                    (const bf16x8*)w2 + ((size_t)(tap * 2 + chunk) * 4) * 64 + lane;
#pragma unroll
                for (int m = 0; m < 4; ++m) a[m] = w2p[m * 64];

                // lane's channel base for this chunk: quad*8 within the 32-chunk
                const float* ip = imgb
                    + (size_t)(chunk * 32 + quad * 8) * 65536
                    + (size_t)(p + kt) * 256 + (q0 + n + lt);
#pragma unroll
                for (int i = 0; i < 4; ++i) {
                    bf16x8 bf;
#pragma unroll
                    for (int j = 0; j < 8; ++j)
                        bf[j] = (bf16_t)(ip[(size_t)j * 65536 + i * 16] * dwv[i]);
#pragma unroll
                    for (int m = 0; m < 4; ++m)
                        acc[m][i] = __builtin_amdgcn_mfma_f32_16x16x32_bf16(
                            a[m], bf, acc[m][i], 0, 0, 0);
                }
            }
        }
    }

    // epilogue: D[row=quad*4+r][col=n] per block; oc = m*16+quad*4+r, q = q0+i*16+n
#pragma unroll
    for (int m = 0; m < 4; ++m) {
#pragma unroll
        for (int r = 0; r < 4; ++r) {
            int oc = m * 16 + quad * 4 + r;
            float bz = bias[oc];
#pragma unroll
            for (int i = 0; i < 4; ++i) {
                int q = q0 + i * 16 + n;
                out[((size_t)(b * 64 + oc) * 254 + p) * 254 + q] = acc[m][i][r] + bz;
            }
        }
    }
}

extern "C" void kernel_launch(void* const* d_in, const int* in_sizes, int n_in,
                              void* d_out, int out_size, void* d_ws, size_t ws_size,
                              hipStream_t stream) {
    const float* img   = (const float*)d_in[0];
    const float* depth = (const float*)d_in[1];
    const float* w     = (const float*)d_in[2];
    const float* bias  = (const float*)d_in[3];
    bf16_t* w2 = (bf16_t*)d_ws;

    repack_w<<<144, 256, 0, stream>>>(w, w2);
    // 4 b * 254 p-rows * 4 q-tiles = 4064 wave-tiles, 4 waves/block
    depthconv_mfma<<<1016, 256, 0, stream>>>(img, depth, w2, bias, (float*)d_out);
}

// Round 3
// 176.937 us; speedup vs baseline: 1.0130x; 1.0130x over previous
//
#include <hip/hip_runtime.h>
#include <hip/hip_bf16.h>

typedef __bf16 bf16_t;
typedef __bf16 bf16x4 __attribute__((ext_vector_type(4)));
typedef __bf16 bf16x8 __attribute__((ext_vector_type(8)));
typedef float f32x4 __attribute__((ext_vector_type(4)));

#define ALPHA 8.3f
#define CPAD 72    // channel dim padded 64->72 (144B stride: 16B-aligned, conflict-free)
#define NCOL 136   // staged columns per block (half row + halo, mult of 4)

// img: [4][64][256][256] f32, depth: [4][1][256][256] f32,
// weight: [64][64][3][3] f32, bias: [1][64] f32, out: [4][64][254][254] f32

// Repack weight -> bf16 A-fragment order [tap(9)][chunk(2)][mblock(4)][lane(64)][j(8)]
//   oc = mblock*16 + (lane&15), c = chunk*32 + (lane>>4)*8 + j
__global__ void repack_w(const float* __restrict__ w, bf16_t* __restrict__ w2) {
    int idx = blockIdx.x * 256 + threadIdx.x;  // 0..36863
    if (idx >= 9 * 2 * 4 * 64 * 8) return;
    int j     = idx & 7;
    int lane  = (idx >> 3) & 63;
    int m     = (idx >> 9) & 3;
    int chunk = (idx >> 11) & 1;
    int tap   = idx >> 12;
    int oc = m * 16 + (lane & 15);
    int c  = chunk * 32 + (lane >> 4) * 8 + j;
    int kt = tap / 3, lt = tap % 3;
    w2[idx] = (bf16_t)w[((oc * 64 + c) * 3 + kt) * 3 + lt];
}

// Block = 128 thr (2 waves): (b, p, half-row). Each wave: 64(oc) x 64(q) tile.
// GEMM per tap: P[oc][pix] = sum_c W*img (raw bf16 B from LDS), then
// acc += dw[tap,pix] * P  (dw scalar per lane since D-col = lane&15).
__global__ __launch_bounds__(128) void depthconv_mfma(
    const float* __restrict__ img, const float* __restrict__ depth,
    const bf16_t* __restrict__ w2, const float* __restrict__ bias,
    float* __restrict__ out)
{
    __shared__ bf16_t lds[3 * NCOL * CPAD];  // 58,752 B -> 2 blocks/CU

    const int tid = threadIdx.x;
    // XCD swizzle: 8 consecutive blocks = same p, all (b,h) -> each XCD sweeps p
    const int p = blockIdx.x >> 3;
    const int r = blockIdx.x & 7;
    const int b = r >> 1;
    const int h = r & 1;
    const int s0 = h ? 120 : 0;  // staged col start (16B-aligned)

    const float* imgb = img + (size_t)b * 64 * 65536;
    const float* dep  = depth + (size_t)b * 65536;

    // ---- stage: img f32 -> bf16 LDS [kt][col][c], in-register 4x4 transpose ----
    // unit = (kt, colg, cg): 4 channels (c0..c0+3) x 4 cols. Lanes vary cg fastest
    // -> ds_write_b64 banks optimal (4 accesses/bank).
    for (int u = tid; u < 3 * 34 * 16; u += 128) {
        int cg   = u & 15;
        int colg = (u >> 4) % 34;
        int kt   = (u >> 4) / 34;
        int c0  = cg * 4;
        int cl0 = colg * 4;
        const float* src = imgb + (size_t)c0 * 65536 + (p + kt) * 256 + s0 + cl0;
        float4 v0 = *(const float4*)src;
        float4 v1 = *(const float4*)(src + 65536);
        float4 v2 = *(const float4*)(src + 2 * 65536);
        float4 v3 = *(const float4*)(src + 3 * 65536);
        bf16_t* dst = lds + (size_t)(kt * NCOL + cl0) * CPAD + c0;
        *(bf16x4*)(dst)            = (bf16x4){(bf16_t)v0.x, (bf16_t)v1.x, (bf16_t)v2.x, (bf16_t)v3.x};
        *(bf16x4*)(dst + CPAD)     = (bf16x4){(bf16_t)v0.y, (bf16_t)v1.y, (bf16_t)v2.y, (bf16_t)v3.y};
        *(bf16x4*)(dst + 2 * CPAD) = (bf16x4){(bf16_t)v0.z, (bf16_t)v1.z, (bf16_t)v2.z, (bf16_t)v3.z};
        *(bf16x4*)(dst + 3 * CPAD) = (bf16x4){(bf16_t)v0.w, (bf16_t)v1.w, (bf16_t)v2.w, (bf16_t)v3.w};
    }
    __syncthreads();

    // ---- compute ----
    const int wv   = tid >> 6;
    const int lane = tid & 63;
    const int n    = lane & 15;
    const int quad = lane >> 4;
    const int q0w  = h * 126 + wv * 64;   // tile col start; 126/127 dup-written identically
    const int clb0 = q0w - s0;            // col offset into LDS tile

    float dc[4];
#pragma unroll
    for (int i = 0; i < 4; ++i)
        dc[i] = dep[(p + 1) * 256 + q0w + 16 * i + n + 1];

    f32x4 acc[4][4];
#pragma unroll
    for (int m = 0; m < 4; ++m)
#pragma unroll
        for (int i = 0; i < 4; ++i)
            acc[m][i] = (f32x4){0.f, 0.f, 0.f, 0.f};
    const f32x4 Z = (f32x4){0.f, 0.f, 0.f, 0.f};

    for (int kt = 0; kt < 3; ++kt) {
        float dwv[3][4];
#pragma unroll
        for (int lt = 0; lt < 3; ++lt)
#pragma unroll
            for (int i = 0; i < 4; ++i) {
                float d = dep[(p + kt) * 256 + q0w + 16 * i + n + lt];
                dwv[lt][i] = __expf(-ALPHA * fabsf(d - dc[i]));
            }
#pragma unroll
        for (int lt = 0; lt < 3; ++lt) {
            const int tap = kt * 3 + lt;
            f32x4 P[4][4];
#pragma unroll
            for (int chunk = 0; chunk < 2; ++chunk) {
                bf16x8 a[4];
                const bf16x8* w2p = (const bf16x8*)w2 + ((size_t)(tap * 2 + chunk) * 4) * 64 + lane;
#pragma unroll
                for (int m = 0; m < 4; ++m) a[m] = w2p[m * 64];
#pragma unroll
                for (int i = 0; i < 4; ++i) {
                    const bf16x8 bf = *(const bf16x8*)(
                        lds + (size_t)(kt * NCOL + clb0 + 16 * i + n + lt) * CPAD
                            + chunk * 32 + quad * 8);
                    if (chunk == 0) {
#pragma unroll
                        for (int m = 0; m < 4; ++m)
                            P[m][i] = __builtin_amdgcn_mfma_f32_16x16x32_bf16(a[m], bf, Z, 0, 0, 0);
                    } else {
#pragma unroll
                        for (int m = 0; m < 4; ++m)
                            P[m][i] = __builtin_amdgcn_mfma_f32_16x16x32_bf16(a[m], bf, P[m][i], 0, 0, 0);
                    }
                }
            }
#pragma unroll
            for (int m = 0; m < 4; ++m)
#pragma unroll
                for (int i = 0; i < 4; ++i)
                    acc[m][i] += dwv[lt][i] * P[m][i];
        }
    }

    // epilogue: D[row=quad*4+r2][col=n]; oc = m*16+quad*4+r2, q = q0w+16i+n
#pragma unroll
    for (int m = 0; m < 4; ++m) {
#pragma unroll
        for (int r2 = 0; r2 < 4; ++r2) {
            int oc = m * 16 + quad * 4 + r2;
            float bz = bias[oc];
#pragma unroll
            for (int i = 0; i < 4; ++i) {
                int q = q0w + 16 * i + n;
                out[((size_t)(b * 64 + oc) * 254 + p) * 254 + q] = acc[m][i][r2] + bz;
            }
        }
    }
}

extern "C" void kernel_launch(void* const* d_in, const int* in_sizes, int n_in,
                              void* d_out, int out_size, void* d_ws, size_t ws_size,
                              hipStream_t stream) {
    const float* img   = (const float*)d_in[0];
    const float* depth = (const float*)d_in[1];
    const float* w     = (const float*)d_in[2];
    const float* bias  = (const float*)d_in[3];
    bf16_t* w2 = (bf16_t*)d_ws;

    repack_w<<<144, 256, 0, stream>>>(w, w2);
    // 254 p-rows x (4 b x 2 halves) = 2032 blocks, 128 thr (2 waves)
    depthconv_mfma<<<2032, 128, 0, stream>>>(img, depth, w2, bias, (float*)d_out);
}

// Round 4
// 167.235 us; speedup vs baseline: 1.0718x; 1.0580x over previous
//
#include <hip/hip_runtime.h>
#include <hip/hip_bf16.h>

typedef __bf16 bf16_t;
typedef __bf16 bf16x4 __attribute__((ext_vector_type(4)));
typedef __bf16 bf16x8 __attribute__((ext_vector_type(8)));
typedef float f32x4 __attribute__((ext_vector_type(4)));

#define ALPHA 8.3f
#define CPAD 72    // bf16 channel stride (144 B): 16B-aligned
#define NCOL 136   // staged cols per half-row (incl. halo)
#define NROW 6     // circular row slots

// img: [4][64][256][256] f32, depth: [4][1][256][256] f32,
// weight: [64][64][3][3] f32, bias: [1][64] f32, out: [4][64][254][254] f32

// Repack weight -> bf16 A-fragment order [tap(9)][chunk(2)][mblock(4)][lane(64)][j(8)]
//   oc = mblock*16 + (lane&15), c = chunk*32 + (lane>>4)*8 + j
__global__ void repack_w(const float* __restrict__ w, bf16_t* __restrict__ w2) {
    int idx = blockIdx.x * 256 + threadIdx.x;  // 0..36863
    if (idx >= 9 * 2 * 4 * 64 * 8) return;
    int j     = idx & 7;
    int lane  = (idx >> 3) & 63;
    int m     = (idx >> 9) & 3;
    int chunk = (idx >> 11) & 1;
    int tap   = idx >> 12;
    int oc = m * 16 + (lane & 15);
    int c  = chunk * 32 + (lane >> 4) * 8 + j;
    int kt = tap / 3, lt = tap % 3;
    w2[idx] = (bf16_t)w[((oc * 64 + c) * 3 + kt) * 3 + lt];
}

// Prefetch 2 img rows (r0, r0+1) into registers: 17 float4/thread, all independent.
__device__ __forceinline__ void stage_issue(const float* __restrict__ imgb, int r0,
                                            int rmax, int s0, int tid, f32x4 sv[5][4]) {
#pragma unroll
    for (int k = 0; k < 5; ++k) {
        int u = tid + (k << 8);
        int ru = u >= 544;
        int v = u - (ru ? 544 : 0);
        int cg = v & 15, colg = v >> 4;      // 4 channels x 4 cols unit
        int row = r0 + ru;
        if (u < 1088 && row <= rmax) {
            const float* src = imgb + (size_t)(cg * 4) * 65536 + row * 256 + s0 + colg * 4;
            sv[k][0] = *(const f32x4*)src;
            sv[k][1] = *(const f32x4*)(src + 65536);
            sv[k][2] = *(const f32x4*)(src + 2 * 65536);
            sv[k][3] = *(const f32x4*)(src + 3 * 65536);
        }
    }
}

// Convert + transpose-commit the prefetched rows to LDS [slot][col][c].
__device__ __forceinline__ void stage_commit(bf16_t* __restrict__ lds, int r0,
                                             int rmax, int tid, const f32x4 sv[5][4]) {
#pragma unroll
    for (int k = 0; k < 5; ++k) {
        int u = tid + (k << 8);
        int ru = u >= 544;
        int v = u - (ru ? 544 : 0);
        int cg = v & 15, colg = v >> 4;
        int row = r0 + ru;
        if (u < 1088 && row <= rmax) {
            int slot = row % NROW;
            bf16_t* dst = lds + (size_t)(slot * NCOL + colg * 4) * CPAD + cg * 4;
#pragma unroll
            for (int i = 0; i < 4; ++i)
                *(bf16x4*)(dst + i * CPAD) =
                    (bf16x4){(bf16_t)sv[k][0][i], (bf16_t)sv[k][1][i],
                             (bf16_t)sv[k][2][i], (bf16_t)sv[k][3][i]};
        }
    }
}

// Block = 256 thr (4 waves), owns (b, half-row h, strip of 8 p-rows).
// Per iteration: prefetch rows p+4,p+5 -> compute rows p,p+1 (wave = (pr,qt),
// 64oc x 64q tile via MFMA; dw applied post-MFMA per tap) -> commit -> barrier.
__global__ __launch_bounds__(256, 1) void depthconv_mfma(
    const float* __restrict__ img, const float* __restrict__ depth,
    const bf16_t* __restrict__ w2, const float* __restrict__ bias,
    float* __restrict__ out)
{
    __shared__ bf16_t lds[NROW * NCOL * CPAD];  // 117,504 B -> 1 block/CU

    const int tid = threadIdx.x;
    // blk%8 = (b,h): each XCD keeps one (b,h) stream -> strip-boundary rows L2-hit
    const int blk   = blockIdx.x;
    const int strip = blk >> 3;
    const int b     = (blk >> 1) & 3;
    const int h     = blk & 1;
    const int p0    = strip * 8;
    const int pend  = min(p0 + 7, 253);
    const int rmax  = pend + 2;          // last img row needed
    const int s0    = h ? 120 : 0;

    const float* imgb = img + (size_t)b * 64 * 65536;
    const float* dep  = depth + (size_t)b * 65536;

    f32x4 sv[5][4];
    // initial fill: rows p0..p0+3
    stage_issue(imgb, p0, rmax, s0, tid, sv);
    stage_commit(lds, p0, rmax, tid, sv);
    stage_issue(imgb, p0 + 2, rmax, s0, tid, sv);
    stage_commit(lds, p0 + 2, rmax, tid, sv);
    __syncthreads();

    const int wv   = tid >> 6;
    const int lane = tid & 63;
    const int pr   = wv >> 1;            // p-row within pair
    const int qt   = wv & 1;             // q-tile within half
    const int n    = lane & 15;
    const int quad = lane >> 4;
    const int q0w  = h * 126 + qt * 64;  // q 126/127 dup-written identically
    const int clb0 = q0w - s0;

    const f32x4 Z = (f32x4){0.f, 0.f, 0.f, 0.f};

    for (int p = p0; p <= pend; p += 2) {
        const int r0 = p + 4;
        const bool st = (r0 <= rmax);
        if (st) stage_issue(imgb, r0, rmax, s0, tid, sv);  // in flight over compute

        const int prow = p + pr;
        float dc[4];
#pragma unroll
        for (int i = 0; i < 4; ++i)
            dc[i] = dep[(prow + 1) * 256 + q0w + 16 * i + n + 1];

        f32x4 acc[4][4];
#pragma unroll
        for (int m = 0; m < 4; ++m)
#pragma unroll
            for (int i = 0; i < 4; ++i) acc[m][i] = Z;

        for (int kt = 0; kt < 3; ++kt) {
            const int rs = (prow + kt) % NROW;
            float dwv[3][4];
#pragma unroll
            for (int lt = 0; lt < 3; ++lt)
#pragma unroll
                for (int i = 0; i < 4; ++i) {
                    float d = dep[(prow + kt) * 256 + q0w + 16 * i + n + lt];
                    dwv[lt][i] = __expf(-ALPHA * fabsf(d - dc[i]));
                }
#pragma unroll
            for (int lt = 0; lt < 3; ++lt) {
                const int tap = kt * 3 + lt;
                f32x4 P[4][4];
#pragma unroll
                for (int chunk = 0; chunk < 2; ++chunk) {
                    bf16x8 a[4];
                    const bf16x8* w2p =
                        (const bf16x8*)w2 + ((size_t)(tap * 2 + chunk) * 4) * 64 + lane;
#pragma unroll
                    for (int m = 0; m < 4; ++m) a[m] = w2p[m * 64];
#pragma unroll
                    for (int i = 0; i < 4; ++i) {
                        const bf16x8 bf = *(const bf16x8*)(
                            lds + (size_t)(rs * NCOL + clb0 + 16 * i + n + lt) * CPAD
                                + chunk * 32 + quad * 8);
                        if (chunk == 0) {
#pragma unroll
                            for (int m = 0; m < 4; ++m)
                                P[m][i] = __builtin_amdgcn_mfma_f32_16x16x32_bf16(
                                    a[m], bf, Z, 0, 0, 0);
                        } else {
#pragma unroll
                            for (int m = 0; m < 4; ++m)
                                P[m][i] = __builtin_amdgcn_mfma_f32_16x16x32_bf16(
                                    a[m], bf, P[m][i], 0, 0, 0);
                        }
                    }
                }
#pragma unroll
                for (int m = 0; m < 4; ++m)
#pragma unroll
                    for (int i = 0; i < 4; ++i)
                        acc[m][i] += dwv[lt][i] * P[m][i];
            }
        }

        // epilogue: D[row=quad*4+r2][col=n]; oc = m*16+quad*4+r2, q = q0w+16i+n
#pragma unroll
        for (int m = 0; m < 4; ++m) {
#pragma unroll
            for (int r2 = 0; r2 < 4; ++r2) {
                int oc = m * 16 + quad * 4 + r2;
                float bz = bias[oc];
#pragma unroll
                for (int i = 0; i < 4; ++i) {
                    int q = q0w + 16 * i + n;
                    out[((size_t)(b * 64 + oc) * 254 + prow) * 254 + q] = acc[m][i][r2] + bz;
                }
            }
        }

        if (st) stage_commit(lds, r0, rmax, tid, sv);
        __syncthreads();
    }
}

extern "C" void kernel_launch(void* const* d_in, const int* in_sizes, int n_in,
                              void* d_out, int out_size, void* d_ws, size_t ws_size,
                              hipStream_t stream) {
    const float* img   = (const float*)d_in[0];
    const float* depth = (const float*)d_in[1];
    const float* w     = (const float*)d_in[2];
    const float* bias  = (const float*)d_in[3];
    bf16_t* w2 = (bf16_t*)d_ws;

    repack_w<<<144, 256, 0, stream>>>(w, w2);
    // 32 strips x 4 b x 2 halves = 256 blocks (1/CU), 256 thr (4 waves)
    depthconv_mfma<<<256, 256, 0, stream>>>(img, depth, w2, bias, (float*)d_out);
}